// Round 4
// baseline (76.871 us; speedup 1.0000x reference)
//
#include <hip/hip_runtime.h>

// Problem constants (match reference)
#define MAX_ATOMS   80
#define MAX_DEGREE  4
#define MAX_RINGS   10
#define RING_SIZE   8
#define RING_FLAT   (MAX_RINGS * RING_SIZE)   // 80
#define EDGE_FLAT   (MAX_ATOMS * MAX_DEGREE)  // 320
#define MOLS_PER_BLOCK 4                      // 1 wave (64 lanes) per molecule

// nb in [-1, 80). Validity via nb >= 0; clamp only for a safe LDS read.
__device__ __forceinline__ float bond_val(int nb, unsigned ma, const unsigned* m) {
    int c = nb < 0 ? 0 : (nb > MAX_ATOMS - 1 ? MAX_ATOMS - 1 : nb);
    return ((nb >= 0) && (ma & m[c])) ? 1.0f : 0.0f;
}

__global__ __launch_bounds__(256) void Find_Ring_Bonds_kernel(
    const float* __restrict__ edges,   // [B, 80, 4] float (int values, -1 = null)
    const int*   __restrict__ rings,   // [B, 10, 8] int  (-1 = pad)
    float*       __restrict__ out,     // [B, 80, 4, 1] float
    int B)
{
    // Wave-private atom -> 10-bit ring-membership table. No cross-wave access,
    // so NO __syncthreads() anywhere: same-wave LDS RAW is ordered by the
    // in-order DS pipe (compiler inserts lgkmcnt waits).
    __shared__ unsigned mtab[MOLS_PER_BLOCK][MAX_ATOMS];

    const int wave = threadIdx.x >> 6;
    const int lane = threadIdx.x & 63;
    const int mol  = blockIdx.x * MOLS_PER_BLOCK + wave;
    if (mol >= B) return;                 // wave-uniform; safe (no barriers)

    unsigned* m = mtab[wave];

    const float4* e4 = (const float4*)(edges + (size_t)mol * EDGE_FLAT);
    float4*       o4 = (float4*)(out   + (size_t)mol * EDGE_FLAT);

    // --- Rings load FIRST: it heads the critical path (mask build -> transpose
    // -> LDS -> gather). 10 lanes x 32B contiguous, coalesced.
    int4 ra = {0,0,0,0}, rb = {0,0,0,0};
    const bool ringlane = (lane < MAX_RINGS);
    if (ringlane) {
        const int4* rp = (const int4*)(rings + (size_t)mol * RING_FLAT + lane * RING_SIZE);
        ra = rp[0];
        rb = rp[1];
    }

    // --- Edge loads second: not needed until the bond phase, so their latency
    // hides under the entire ring/transpose phase (counted vmcnt release).
    const bool hi = (lane < MAX_ATOMS - 64);    // lanes 0..15 own atoms 64..79
    float4 ev0 = e4[lane];
    float4 ev1;
    if (hi) ev1 = e4[64 + lane];

    // --- Ring phase: lane r (<10) builds an 80-bit membership mask of ring r.
    // Pure VALU, no atomics.
    unsigned w0 = 0u, w1 = 0u, w2 = 0u;   // atoms [0,32) [32,64) [64,80)
    if (ringlane) {
        int vs[8] = {ra.x, ra.y, ra.z, ra.w, rb.x, rb.y, rb.z, rb.w};
        #pragma unroll
        for (int s = 0; s < 8; ++s) {
            int v = vs[s];
            unsigned b = 1u << (v & 31);           // HW shifts mod 32
            w0 |= (v >= 0 && v < 32) ? b : 0u;
            w1 |= (v >= 32 && v < 64) ? b : 0u;
            w2 |= (v >= 64)           ? b : 0u;
        }
    }

    // --- Transpose ring-major -> atom-major via readlane broadcast.
    // m0 = ring mask of atom `lane`; m1 = ring mask of atom `64+lane` (lane<16).
    unsigned m0 = 0u, m1 = 0u;
    #pragma unroll
    for (int r = 0; r < MAX_RINGS; ++r) {
        unsigned rw0 = (unsigned)__builtin_amdgcn_readlane((int)w0, r);
        unsigned rw1 = (unsigned)__builtin_amdgcn_readlane((int)w1, r);
        unsigned rw2 = (unsigned)__builtin_amdgcn_readlane((int)w2, r);
        unsigned long long lo64 = ((unsigned long long)rw1 << 32) | (unsigned long long)rw0;
        m0 |= ((unsigned)(lo64 >> lane) & 1u) << r;   // v_lshrrev_b64, 1 instr
        m1 |= ((rw2 >> lane) & 1u) << r;
    }

    // --- Publish the 80-entry lookup table (plain stores, <=2-way bank = free)
    m[lane] = m0;
    if (hi) m[64 + lane] = m1;

    // --- Bond phase: per-atom float4 edge pass (coalesced 16B/lane) ---
    {
        float4 r;
        r.x = bond_val((int)ev0.x, m0, m);
        r.y = bond_val((int)ev0.y, m0, m);
        r.z = bond_val((int)ev0.z, m0, m);
        r.w = bond_val((int)ev0.w, m0, m);
        o4[lane] = r;
    }
    if (hi) {
        float4 r;
        r.x = bond_val((int)ev1.x, m1, m);
        r.y = bond_val((int)ev1.y, m1, m);
        r.z = bond_val((int)ev1.z, m1, m);
        r.w = bond_val((int)ev1.w, m1, m);
        o4[64 + lane] = r;
    }
}

extern "C" void kernel_launch(void* const* d_in, const int* in_sizes, int n_in,
                              void* d_out, int out_size, void* d_ws, size_t ws_size,
                              hipStream_t stream) {
    const float* edges = (const float*)d_in[0];   // [B,80,4] float32
    const int*   rings = (const int*)d_in[1];     // [B,10,8] int32
    float*       out   = (float*)d_out;           // [B,80,4,1] float32

    const int B = in_sizes[0] / EDGE_FLAT;        // 16384
    const int grid = (B + MOLS_PER_BLOCK - 1) / MOLS_PER_BLOCK;

    Find_Ring_Bonds_kernel<<<grid, 256, 0, stream>>>(edges, rings, out, B);
}

// Round 6
// 76.563 us; speedup vs baseline: 1.0040x; 1.0040x over previous
//
#include <hip/hip_runtime.h>

// Problem constants (match reference)
#define MAX_ATOMS   80
#define MAX_DEGREE  4
#define MAX_RINGS   10
#define RING_SIZE   8
#define RING_FLAT   (MAX_RINGS * RING_SIZE)   // 80 ints per molecule
#define EDGE_FLAT   (MAX_ATOMS * MAX_DEGREE)  // 320 floats per molecule
#define WAVES_PER_BLOCK 4
#define MOLS_PER_WAVE   2                     // 2 molecules per 64-lane wave
#define MOLS_PER_BLOCK  (WAVES_PER_BLOCK * MOLS_PER_WAVE)  // 8

// nb in [-1, 80). Validity via nb >= 0; clamp only for a safe LDS read.
__device__ __forceinline__ float bond_val(int nb, unsigned ma, const unsigned* mt) {
    int c = nb < 0 ? 0 : (nb > MAX_ATOMS - 1 ? MAX_ATOMS - 1 : nb);
    return ((nb >= 0) && (ma & mt[c])) ? 1.0f : 0.0f;
}

__global__ __launch_bounds__(256) void Find_Ring_Bonds_kernel(
    const float* __restrict__ edges,   // [B, 80, 4] float (int values, -1 = null)
    const int*   __restrict__ rings,   // [B, 10, 8] int  (-1 = pad)
    float*       __restrict__ out,     // [B, 80, 4, 1] float
    int B)
{
    // Per-wave [2 molecules][80 atoms] -> 10-bit ring-membership table.
    // Barriers reinstated around the atomic scatter: round-5's barrier-free
    // ds_or -> ds_read ordering produced sparse mismatches; round-0 vs round-4
    // A/B showed barriers cost ~0 here, so take the safe ordering.
    __shared__ unsigned mtab[WAVES_PER_BLOCK][2 * MAX_ATOMS];

    const int wave = threadIdx.x >> 6;
    const int lane = threadIdx.x & 63;
    const int pm   = (blockIdx.x * WAVES_PER_BLOCK + wave) * MOLS_PER_WAVE;
    const bool live = (pm < B);
    const int nmol  = !live ? 0 : ((pm + 1 < B) ? 2 : 1);
    const int limit = nmol * MAX_ATOMS;   // atom float4-slots AND ring ints (both 80/mol)

    unsigned* m = mtab[wave];

    const float4* e4 = (const float4*)(edges + (size_t)pm * EDGE_FLAT);
    float4*       o4 = (float4*)(out   + (size_t)pm * EDGE_FLAT);

    // ---- Rings load first: heads the critical path (scatter -> gather).
    // 2 molecules' rings are contiguous: limit ints = limit/4 int4 slots.
    int4 rv = {-1, -1, -1, -1};
    const bool rl = lane < (limit >> 2);          // 40 lanes (20 on odd tail)
    if (rl) rv = ((const int4*)(rings + (size_t)pm * RING_FLAT))[lane];

    // ---- Edge loads second: latency hides under the ring phase.
    const bool v0 = lane < limit;
    const bool v1 = (64 + lane) < limit;
    const bool v2 = (lane < 32) && ((128 + lane) < limit);
    float4 ev0, ev1, ev2;
    if (v0) ev0 = e4[lane];
    if (v1) ev1 = e4[64 + lane];
    if (v2) ev2 = e4[128 + lane];

    // ---- Zero the 160-entry table (plain stores, conflict-free).
    if (live) {
        m[lane]      = 0u;
        m[64 + lane] = 0u;
        if (lane < 32) m[128 + lane] = 0u;
    }
    __syncthreads();   // zero complete before scatter (write vs RMW ordering)

    // ---- Scatter ring membership: flat ring-int index ej in [0,160);
    // mol offset = 80 for ej>=80; ring id within mol = (ej - moff) >> 3.
    if (rl) {
        const int e0 = lane * 4;
        const int vs[4] = {rv.x, rv.y, rv.z, rv.w};
        #pragma unroll
        for (int j = 0; j < 4; ++j) {
            const int ej   = e0 + j;
            const int moff = (ej >= MAX_ATOMS) ? MAX_ATOMS : 0;
            const unsigned bit = 1u << ((ej - moff) >> 3);
            const int v = vs[j];
            if (v >= 0) atomicOr(&m[moff + v], bit);  // ds_or_b32, no return
        }
    }
    __syncthreads();   // scatter complete before any table read

    // ---- Bond phase: atom slot f in [0,160); table flat index of atom == f.
    if (v0) {                                    // f = lane < 80: molecule 0
        const unsigned ma = m[lane];
        float4 r;
        r.x = bond_val((int)ev0.x, ma, m);
        r.y = bond_val((int)ev0.y, ma, m);
        r.z = bond_val((int)ev0.z, ma, m);
        r.w = bond_val((int)ev0.w, ma, m);
        o4[lane] = r;
    }
    if (v1) {
        const int f = 64 + lane;                 // [64,128): mol 0 or mol 1
        const int moff = (f >= MAX_ATOMS) ? MAX_ATOMS : 0;
        const unsigned ma = m[f];
        float4 r;
        r.x = bond_val((int)ev1.x, ma, m + moff);
        r.y = bond_val((int)ev1.y, ma, m + moff);
        r.z = bond_val((int)ev1.z, ma, m + moff);
        r.w = bond_val((int)ev1.w, ma, m + moff);
        o4[f] = r;
    }
    if (v2) {
        const int f = 128 + lane;                // [128,160): always mol 1
        const unsigned ma = m[f];
        float4 r;
        r.x = bond_val((int)ev2.x, ma, m + MAX_ATOMS);
        r.y = bond_val((int)ev2.y, ma, m + MAX_ATOMS);
        r.z = bond_val((int)ev2.z, ma, m + MAX_ATOMS);
        r.w = bond_val((int)ev2.w, ma, m + MAX_ATOMS);
        o4[f] = r;
    }
}

extern "C" void kernel_launch(void* const* d_in, const int* in_sizes, int n_in,
                              void* d_out, int out_size, void* d_ws, size_t ws_size,
                              hipStream_t stream) {
    const float* edges = (const float*)d_in[0];   // [B,80,4] float32
    const int*   rings = (const int*)d_in[1];     // [B,10,8] int32
    float*       out   = (float*)d_out;           // [B,80,4,1] float32

    const int B = in_sizes[0] / EDGE_FLAT;        // 16384
    const int grid = (B + MOLS_PER_BLOCK - 1) / MOLS_PER_BLOCK;

    Find_Ring_Bonds_kernel<<<grid, 256, 0, stream>>>(edges, rings, out, B);
}